// Round 1
// baseline (1593.828 us; speedup 1.0000x reference)
//
#include <hip/hip_runtime.h>
#include <cstddef>
#include <cstdint>

// Problem constants (B=2, S=2048, D=1024, H=16, hd=64)
constexpr int Bb = 2, Ss = 2048, Dd = 1024, Hh = 16, HD = 64;
constexpr int Mm = Bb * Ss;  // 4096 rows

// ---------------- amax (abs-max) reduction ----------------
__global__ void amax_kernel(const float* __restrict__ x, int n, unsigned* __restrict__ out) {
    float m = 0.f;
    int stride = gridDim.x * blockDim.x;
    for (int i = blockIdx.x * blockDim.x + threadIdx.x; i < n; i += stride)
        m = fmaxf(m, fabsf(x[i]));
    #pragma unroll
    for (int off = 32; off > 0; off >>= 1)
        m = fmaxf(m, __shfl_down(m, off, 64));
    __shared__ float sm[8];
    int lane = threadIdx.x & 63, wid = threadIdx.x >> 6;
    if (lane == 0) sm[wid] = m;
    __syncthreads();
    if (threadIdx.x == 0) {
        float mm = sm[0];
        int nw = blockDim.x >> 6;
        for (int i = 1; i < nw; i++) mm = fmaxf(mm, sm[i]);
        // float bits compare as unsigned for non-negative floats
        atomicMax(out, __float_as_uint(mm));
    }
}

// scale = max(amax / 127, 1e-8)  (use true division to match reference exactly)
__global__ void scale_kernel(float* ws, int amax_base, int scale_base, int cnt) {
    int i = threadIdx.x;
    if (i < cnt) ws[scale_base + i] = fmaxf(ws[amax_base + i] / 127.0f, 1e-8f);
}

// y = rint(x/s)*s   (rintf = ties-to-even, matches jnp.round)
__global__ void quant_kernel(const float* __restrict__ x, float* __restrict__ y,
                             const float* __restrict__ sp, int n) {
    float s = sp[0];
    int stride = gridDim.x * blockDim.x;
    for (int i = blockIdx.x * blockDim.x + threadIdx.x; i < n; i += stride)
        y[i] = rintf(x[i] / s) * s;
}

// ---------------- GEMM: C[M,N] = A[M,K] * B[N,K]^T + bias[N] ----------------
// BM=BN=64, BK=16, 256 threads, 4x4 micro-tile per thread.
#define GBM 64
#define GBN 64
#define GBK 16
__global__ __launch_bounds__(256) void gemm_bt(const float* __restrict__ A,
                                               const float* __restrict__ B,
                                               const float* __restrict__ bias,
                                               float* __restrict__ C,
                                               int M, int N, int K) {
    __shared__ float As[GBK][GBM + 1];
    __shared__ float Bs[GBK][GBN + 1];
    const int bm = blockIdx.y * GBM, bn = blockIdx.x * GBN;
    const int t = threadIdx.x;
    const int tx = t & 15, ty = t >> 4;
    const int lcol = t & 15;   // k within tile
    const int lrow = t >> 4;   // 0..15

    float acc[4][4] = {};
    for (int k0 = 0; k0 < K; k0 += GBK) {
        #pragma unroll
        for (int p = 0; p < 4; p++) {
            int r = lrow + p * 16;
            As[lcol][r] = A[(size_t)(bm + r) * K + k0 + lcol];
            Bs[lcol][r] = B[(size_t)(bn + r) * K + k0 + lcol];
        }
        __syncthreads();
        #pragma unroll
        for (int kk = 0; kk < GBK; kk++) {
            float a[4], b[4];
            #pragma unroll
            for (int i = 0; i < 4; i++) a[i] = As[kk][ty * 4 + i];
            #pragma unroll
            for (int j = 0; j < 4; j++) b[j] = Bs[kk][tx * 4 + j];
            #pragma unroll
            for (int i = 0; i < 4; i++)
                #pragma unroll
                for (int j = 0; j < 4; j++) acc[i][j] = fmaf(a[i], b[j], acc[i][j]);
        }
        __syncthreads();
    }
    #pragma unroll
    for (int i = 0; i < 4; i++) {
        int m = bm + ty * 4 + i;
        #pragma unroll
        for (int j = 0; j < 4; j++) {
            int n = bn + tx * 4 + j;
            C[(size_t)m * N + n] = acc[i][j] + bias[n];
        }
    }
}

// ---------------- Flash attention (f32, online softmax) ----------------
// grid: (S/64, H, B); 256 threads; each thread owns 4 q-rows x 4 cols.
__global__ __launch_bounds__(256) void attn_kernel(const float* __restrict__ Q,
                                                   const float* __restrict__ Kt,
                                                   const float* __restrict__ V,
                                                   const float* __restrict__ mask,
                                                   float* __restrict__ Ob) {
    __shared__ float Qs[64][HD + 1];
    __shared__ float KPs[64][HD + 1];  // K tile, reused as P tile
    __shared__ float Vs[64][HD + 1];
    __shared__ float mbias[64];
    const int b = blockIdx.z, h = blockIdx.y, q0 = blockIdx.x * 64;
    const int t = threadIdx.x;
    const int tx = t & 15, ty = t >> 4;
    const size_t base = ((size_t)b * Ss) * Dd + (size_t)h * HD;

    {   // load Q tile, pre-scaled by 1/sqrt(hd) = 0.125
        int r = t >> 2, c0 = (t & 3) * 16;
        const float* src = Q + base + (size_t)(q0 + r) * Dd + c0;
        #pragma unroll
        for (int c = 0; c < 16; c++) Qs[r][c0 + c] = src[c] * 0.125f;
    }

    float m_i[4], l_i[4], acc[4][4];
    #pragma unroll
    for (int i = 0; i < 4; i++) {
        m_i[i] = -INFINITY; l_i[i] = 0.f;
        #pragma unroll
        for (int j = 0; j < 4; j++) acc[i][j] = 0.f;
    }

    for (int k0 = 0; k0 < Ss; k0 += 64) {
        __syncthreads();  // protect KPs/Vs from previous iteration's readers
        {   // load K and V tiles
            int r = t >> 2, c0 = (t & 3) * 16;
            const float* ksrc = Kt + base + (size_t)(k0 + r) * Dd + c0;
            const float* vsrc = V  + base + (size_t)(k0 + r) * Dd + c0;
            #pragma unroll
            for (int c = 0; c < 16; c++) { KPs[r][c0 + c] = ksrc[c]; Vs[r][c0 + c] = vsrc[c]; }
            if (t < 64) mbias[t] = (1.0f - mask[b * Ss + k0 + t]) * -10000.0f;
        }
        __syncthreads();

        // S tile: s[i][j] = sum_d Qs[qrow][d] * KPs[krow][d]  (+ mask bias)
        float s[4][4];
        #pragma unroll
        for (int i = 0; i < 4; i++)
            #pragma unroll
            for (int j = 0; j < 4; j++) s[i][j] = mbias[tx * 4 + j];
        for (int d = 0; d < HD; d++) {
            float a[4], bb[4];
            #pragma unroll
            for (int i = 0; i < 4; i++) a[i] = Qs[ty * 4 + i][d];
            #pragma unroll
            for (int j = 0; j < 4; j++) bb[j] = KPs[tx * 4 + j][d];
            #pragma unroll
            for (int i = 0; i < 4; i++)
                #pragma unroll
                for (int j = 0; j < 4; j++) s[i][j] = fmaf(a[i], bb[j], s[i][j]);
        }

        // online softmax update (row groups = 16 consecutive lanes -> shfl_xor width 16)
        float p[4][4];
        #pragma unroll
        for (int i = 0; i < 4; i++) {
            float tm = fmaxf(fmaxf(s[i][0], s[i][1]), fmaxf(s[i][2], s[i][3]));
            #pragma unroll
            for (int off = 8; off > 0; off >>= 1) tm = fmaxf(tm, __shfl_xor(tm, off, 16));
            float mnew = fmaxf(m_i[i], tm);
            float alpha = expf(m_i[i] - mnew);  // first tile: exp(-inf)=0
            float r = 0.f;
            #pragma unroll
            for (int j = 0; j < 4; j++) { p[i][j] = expf(s[i][j] - mnew); r += p[i][j]; }
            #pragma unroll
            for (int off = 8; off > 0; off >>= 1) r += __shfl_xor(r, off, 16);
            l_i[i] = l_i[i] * alpha + r;
            m_i[i] = mnew;
            #pragma unroll
            for (int j = 0; j < 4; j++) acc[i][j] *= alpha;
        }

        __syncthreads();  // all threads done reading KPs as K
        #pragma unroll
        for (int i = 0; i < 4; i++)
            #pragma unroll
            for (int j = 0; j < 4; j++) KPs[ty * 4 + i][tx * 4 + j] = p[i][j];
        __syncthreads();

        // O += P * V
        for (int kj = 0; kj < 64; kj++) {
            float vv[4];
            #pragma unroll
            for (int j = 0; j < 4; j++) vv[j] = Vs[kj][tx * 4 + j];
            #pragma unroll
            for (int i = 0; i < 4; i++) {
                float pp = KPs[ty * 4 + i][kj];
                #pragma unroll
                for (int j = 0; j < 4; j++) acc[i][j] = fmaf(pp, vv[j], acc[i][j]);
            }
        }
    }

    // normalize and write out: attn[b, q, h*64 + e]
    #pragma unroll
    for (int i = 0; i < 4; i++) {
        float inv = 1.0f / l_i[i];
        size_t row = base + (size_t)(q0 + ty * 4 + i) * Dd;
        #pragma unroll
        for (int j = 0; j < 4; j++)
            Ob[row + tx * 4 + j] = acc[i][j] * inv;
    }
}

// ---------------- launch ----------------
extern "C" void kernel_launch(void* const* d_in, const int* in_sizes, int n_in,
                              void* d_out, int out_size, void* d_ws, size_t ws_size,
                              hipStream_t stream) {
    const float* hidden = (const float*)d_in[0];
    const float* mask   = (const float*)d_in[1];
    const float* Wq = (const float*)d_in[2];
    const float* bq = (const float*)d_in[3];
    const float* Wk = (const float*)d_in[4];
    const float* bk = (const float*)d_in[5];
    const float* Wv = (const float*)d_in[6];
    const float* bv = (const float*)d_in[7];
    const float* Wo = (const float*)d_in[8];
    const float* bo = (const float*)d_in[9];
    float* out = (float*)d_out;

    char* ws = (char*)d_ws;
    float* scal = (float*)ws;  // [0..5]=amax slots, [8..13]=scale slots
    size_t off = 1024;
    const size_t szH = (size_t)Mm * Dd * sizeof(float);   // 16.78 MB
    const size_t szW = (size_t)Dd * Dd * sizeof(float);   // 4.19 MB
    float* hq  = (float*)(ws + off); off += szH;  // quantized hidden; reused for quantized attn
    float* Wqq = (float*)(ws + off); off += szW;
    float* Wkq = (float*)(ws + off); off += szW;
    float* Wvq = (float*)(ws + off); off += szW;
    float* Woq = (float*)(ws + off); off += szW;
    float* qb  = (float*)(ws + off); off += szH;
    float* kb  = (float*)(ws + off); off += szH;
    float* vb  = (float*)(ws + off); off += szH;
    float* ab  = (float*)(ws + off); off += szH;

    hipMemsetAsync(scal, 0, 64, stream);  // zero amax slots (graph-capture safe)

    const int nH = Mm * Dd, nW = Dd * Dd;
    amax_kernel<<<512, 256, 0, stream>>>(hidden, nH, (unsigned*)(scal + 0));
    amax_kernel<<<256, 256, 0, stream>>>(Wq, nW, (unsigned*)(scal + 1));
    amax_kernel<<<256, 256, 0, stream>>>(Wk, nW, (unsigned*)(scal + 2));
    amax_kernel<<<256, 256, 0, stream>>>(Wv, nW, (unsigned*)(scal + 3));
    amax_kernel<<<256, 256, 0, stream>>>(Wo, nW, (unsigned*)(scal + 4));
    scale_kernel<<<1, 64, 0, stream>>>(scal, 0, 8, 5);

    quant_kernel<<<1024, 256, 0, stream>>>(hidden, hq, scal + 8, nH);
    quant_kernel<<<512, 256, 0, stream>>>(Wq, Wqq, scal + 9,  nW);
    quant_kernel<<<512, 256, 0, stream>>>(Wk, Wkq, scal + 10, nW);
    quant_kernel<<<512, 256, 0, stream>>>(Wv, Wvq, scal + 11, nW);
    quant_kernel<<<512, 256, 0, stream>>>(Wo, Woq, scal + 12, nW);

    dim3 gg(Dd / GBN, Mm / GBM);
    gemm_bt<<<gg, 256, 0, stream>>>(hq, Wqq, bq, qb, Mm, Dd, Dd);
    gemm_bt<<<gg, 256, 0, stream>>>(hq, Wkq, bk, kb, Mm, Dd, Dd);
    gemm_bt<<<gg, 256, 0, stream>>>(hq, Wvq, bv, vb, Mm, Dd, Dd);

    dim3 ga(Ss / 64, Hh, Bb);
    attn_kernel<<<ga, 256, 0, stream>>>(qb, kb, vb, mask, ab);

    amax_kernel<<<512, 256, 0, stream>>>(ab, nH, (unsigned*)(scal + 5));
    scale_kernel<<<1, 64, 0, stream>>>(scal, 5, 13, 1);
    quant_kernel<<<1024, 256, 0, stream>>>(ab, hq, scal + 13, nH);
    gemm_bt<<<gg, 256, 0, stream>>>(hq, Woq, bo, out, Mm, Dd, Dd);
}

// Round 2
// 908.827 us; speedup vs baseline: 1.7537x; 1.7537x over previous
//
#include <hip/hip_runtime.h>
#include <cstddef>
#include <cstdint>

// Problem constants (B=2, S=2048, D=1024, H=16, hd=64)
constexpr int Bb = 2, Ss = 2048, Dd = 1024, Hh = 16, HD = 64;
constexpr int Mm = Bb * Ss;  // 4096 rows

typedef int v4i __attribute__((ext_vector_type(4)));

// ---------------- amax (abs-max) reduction ----------------
__global__ void amax_kernel(const float* __restrict__ x, int n, unsigned* __restrict__ out) {
    float m = 0.f;
    int stride = gridDim.x * blockDim.x;
    for (int i = blockIdx.x * blockDim.x + threadIdx.x; i < n; i += stride)
        m = fmaxf(m, fabsf(x[i]));
    #pragma unroll
    for (int off = 32; off > 0; off >>= 1)
        m = fmaxf(m, __shfl_down(m, off, 64));
    __shared__ float sm[8];
    int lane = threadIdx.x & 63, wid = threadIdx.x >> 6;
    if (lane == 0) sm[wid] = m;
    __syncthreads();
    if (threadIdx.x == 0) {
        float mm = sm[0];
        int nw = blockDim.x >> 6;
        for (int i = 1; i < nw; i++) mm = fmaxf(mm, sm[i]);
        atomicMax(out, __float_as_uint(mm));  // float bits compare as uint for >=0
    }
}

// scale = max(amax / 127, 1e-8)
__global__ void scale_kernel(float* ws, int amax_base, int scale_base, int cnt) {
    int i = threadIdx.x;
    if (i < cnt) ws[scale_base + i] = fmaxf(ws[amax_base + i] / 127.0f, 1e-8f);
}

// q = (int8) rint(x/s)   (exact: |x/s| <= 127 by construction)
__global__ void quant8_kernel(const float* __restrict__ x, char* __restrict__ y,
                              const float* __restrict__ sp, int n4) {
    float s = sp[0];
    int stride = gridDim.x * blockDim.x;
    const float4* x4 = (const float4*)x;
    char4* y4 = (char4*)y;
    for (int i = blockIdx.x * blockDim.x + threadIdx.x; i < n4; i += stride) {
        float4 v = x4[i];
        char4 q;
        q.x = (char)(int)rintf(v.x / s);
        q.y = (char)(int)rintf(v.y / s);
        q.z = (char)(int)rintf(v.z / s);
        q.w = (char)(int)rintf(v.w / s);
        y4[i] = q;
    }
}

// ---------------- int8 MFMA GEMM: C[M,N] = (A_i8[M,K] . B_i8[N,K]^T) * (sA*sB) + bias[N]
// 128x128 tile, 4 waves (2x2 of 64x64), BK=64, mfma_i32_16x16x64_i8.
// Staging via global_load_lds(16B) with XOR source-swizzle so ds_read_b128 is balanced.
#define GLOAD_LDS16(g, l) __builtin_amdgcn_global_load_lds( \
    (const __attribute__((address_space(1))) unsigned int*)(g), \
    (__attribute__((address_space(3))) unsigned int*)(l), 16, 0, 0)

__global__ __launch_bounds__(256) void gemm_i8(const char* __restrict__ A,
                                               const char* __restrict__ Bw,
                                               const float* __restrict__ bias,
                                               const float* __restrict__ sA,
                                               const float* __restrict__ sB,
                                               float* __restrict__ C,
                                               int M, int N, int K) {
    __shared__ alignas(16) char At[128 * 64];
    __shared__ alignas(16) char Bt[128 * 64];
    const int t = threadIdx.x, lane = t & 63, w = t >> 6;
    const int bm = blockIdx.y * 128, bn = blockIdx.x * 128;
    const int wm = (w >> 1) * 64, wn = (w & 1) * 64;
    const int lr = lane & 15, kq = lane >> 4;

    const v4i vzero = {0, 0, 0, 0};
    v4i acc[4][4];
    #pragma unroll
    for (int mt = 0; mt < 4; mt++)
        #pragma unroll
        for (int nt = 0; nt < 4; nt++) acc[mt][nt] = vzero;

    const int rs = w * 16 + (lane >> 2);  // staged row (wave-contiguous for lds dest rule)
    const int cc = lane & 3;              // 16B chunk position in LDS

    for (int k0 = 0; k0 < K; k0 += 64) {
        __syncthreads();
        #pragma unroll
        for (int h = 0; h < 2; h++) {
            int r = rs + h * 64;
            int cs = cc ^ ((r >> 1) & 3);  // source-side XOR swizzle
            const char* ga = A  + (size_t)(bm + r) * K + k0 + cs * 16;
            const char* gb = Bw + (size_t)(bn + r) * K + k0 + cs * 16;
            GLOAD_LDS16(ga, At + r * 64 + cc * 16);
            GLOAD_LDS16(gb, Bt + r * 64 + cc * 16);
        }
        __syncthreads();

        v4i af[4], bf[4];
        #pragma unroll
        for (int mt = 0; mt < 4; mt++) {
            int row = wm + mt * 16 + lr;
            af[mt] = *(const v4i*)(At + row * 64 + ((kq ^ ((row >> 1) & 3)) << 4));
        }
        #pragma unroll
        for (int nt = 0; nt < 4; nt++) {
            int row = wn + nt * 16 + lr;
            bf[nt] = *(const v4i*)(Bt + row * 64 + ((kq ^ ((row >> 1) & 3)) << 4));
        }
        #pragma unroll
        for (int mt = 0; mt < 4; mt++)
            #pragma unroll
            for (int nt = 0; nt < 4; nt++)
                acc[mt][nt] = __builtin_amdgcn_mfma_i32_16x16x64_i8(af[mt], bf[nt], acc[mt][nt], 0, 0, 0);
    }

    const float sc = sA[0] * sB[0];
    #pragma unroll
    for (int nt = 0; nt < 4; nt++) {
        int n = bn + wn + nt * 16 + lr;
        float bv = bias[n];
        #pragma unroll
        for (int mt = 0; mt < 4; mt++) {
            #pragma unroll
            for (int rg = 0; rg < 4; rg++) {
                int m = bm + wm + mt * 16 + kq * 4 + rg;  // C/D: row=(lane>>4)*4+reg, col=lane&15
                C[(size_t)m * N + n] = (float)acc[mt][nt][rg] * sc + bv;
            }
        }
    }
}

// ---------------- Flash attention (f32, online softmax) ----------------
// Transposed Q/K LDS tiles [d][row] (stride 68 -> aligned float4, balanced banks);
// P kept in registers, broadcast via __shfl for the PV product.
__global__ __launch_bounds__(256) void attn_kernel(const float* __restrict__ Qg,
                                                   const float* __restrict__ Kg,
                                                   const float* __restrict__ Vg,
                                                   const float* __restrict__ mask,
                                                   float* __restrict__ Ob) {
    __shared__ alignas(16) float Qt[64][68];  // [d][qrow]
    __shared__ alignas(16) float Kt[64][68];  // [d][krow]
    __shared__ alignas(16) float Vs[64][68];  // [krow][e]
    __shared__ float mbias[64];
    const int b = blockIdx.z, h = blockIdx.y, q0 = blockIdx.x * 64;
    const int t = threadIdx.x;
    const int tx = t & 15, ty = t >> 4;
    const size_t base = ((size_t)b * Ss) * Dd + (size_t)h * HD;

    {   // load + transpose Q tile, pre-scaled by 1/sqrt(hd)
        int r = t >> 2, c0 = (t & 3) * 16;
        const float4* src = (const float4*)(Qg + base + (size_t)(q0 + r) * Dd + c0);
        #pragma unroll
        for (int c4 = 0; c4 < 4; c4++) {
            float4 v = src[c4];
            Qt[c0 + c4 * 4 + 0][r] = v.x * 0.125f;
            Qt[c0 + c4 * 4 + 1][r] = v.y * 0.125f;
            Qt[c0 + c4 * 4 + 2][r] = v.z * 0.125f;
            Qt[c0 + c4 * 4 + 3][r] = v.w * 0.125f;
        }
    }

    float m_i[4], l_i[4], acc[4][4];
    #pragma unroll
    for (int i = 0; i < 4; i++) {
        m_i[i] = -INFINITY; l_i[i] = 0.f;
        #pragma unroll
        for (int j = 0; j < 4; j++) acc[i][j] = 0.f;
    }

    for (int k0 = 0; k0 < Ss; k0 += 64) {
        __syncthreads();  // previous iteration's readers done with Kt/Vs (also covers Q load)
        {
            int r = t >> 2, c0 = (t & 3) * 16;
            const float4* ks = (const float4*)(Kg + base + (size_t)(k0 + r) * Dd + c0);
            const float4* vsrc = (const float4*)(Vg + base + (size_t)(k0 + r) * Dd + c0);
            float4* vdst = (float4*)&Vs[r][c0];
            #pragma unroll
            for (int c4 = 0; c4 < 4; c4++) {
                float4 kv = ks[c4];
                Kt[c0 + c4 * 4 + 0][r] = kv.x;
                Kt[c0 + c4 * 4 + 1][r] = kv.y;
                Kt[c0 + c4 * 4 + 2][r] = kv.z;
                Kt[c0 + c4 * 4 + 3][r] = kv.w;
                vdst[c4] = vsrc[c4];
            }
            if (t < 64) mbias[t] = (1.0f - mask[b * Ss + k0 + t]) * -10000.0f;
        }
        __syncthreads();

        // S tile via transposed LDS: float4 reads along d
        float s_[4][4];
        #pragma unroll
        for (int i = 0; i < 4; i++)
            #pragma unroll
            for (int j = 0; j < 4; j++) s_[i][j] = mbias[tx * 4 + j];
        #pragma unroll 4
        for (int d = 0; d < HD; d++) {
            float4 qa = *(const float4*)&Qt[d][ty * 4];
            float4 kb = *(const float4*)&Kt[d][tx * 4];
            float a_[4] = {qa.x, qa.y, qa.z, qa.w};
            float b_[4] = {kb.x, kb.y, kb.z, kb.w};
            #pragma unroll
            for (int i = 0; i < 4; i++)
                #pragma unroll
                for (int j = 0; j < 4; j++) s_[i][j] = fmaf(a_[i], b_[j], s_[i][j]);
        }

        // online softmax update (row group = 16 consecutive lanes)
        float p[4][4];
        #pragma unroll
        for (int i = 0; i < 4; i++) {
            float tm = fmaxf(fmaxf(s_[i][0], s_[i][1]), fmaxf(s_[i][2], s_[i][3]));
            #pragma unroll
            for (int off = 8; off > 0; off >>= 1) tm = fmaxf(tm, __shfl_xor(tm, off, 16));
            float mnew = fmaxf(m_i[i], tm);
            float alpha = expf(m_i[i] - mnew);
            float r = 0.f;
            #pragma unroll
            for (int j = 0; j < 4; j++) { p[i][j] = expf(s_[i][j] - mnew); r += p[i][j]; }
            #pragma unroll
            for (int off = 8; off > 0; off >>= 1) r += __shfl_xor(r, off, 16);
            l_i[i] = l_i[i] * alpha + r;
            m_i[i] = mnew;
            #pragma unroll
            for (int j = 0; j < 4; j++) acc[i][j] *= alpha;
        }

        // O += P * V, P broadcast via shuffle (P[ty*4+i][kc*4+j] lives in lane ty*16+kc, reg j)
        for (int kc = 0; kc < 16; kc++) {
            int srcl = (t & 0xF0) | kc;
            #pragma unroll
            for (int j = 0; j < 4; j++) {
                int kj = kc * 4 + j;
                float4 vv = *(const float4*)&Vs[kj][tx * 4];
                float pp0 = __shfl(p[0][j], srcl, 64);
                float pp1 = __shfl(p[1][j], srcl, 64);
                float pp2 = __shfl(p[2][j], srcl, 64);
                float pp3 = __shfl(p[3][j], srcl, 64);
                acc[0][0] = fmaf(pp0, vv.x, acc[0][0]); acc[0][1] = fmaf(pp0, vv.y, acc[0][1]);
                acc[0][2] = fmaf(pp0, vv.z, acc[0][2]); acc[0][3] = fmaf(pp0, vv.w, acc[0][3]);
                acc[1][0] = fmaf(pp1, vv.x, acc[1][0]); acc[1][1] = fmaf(pp1, vv.y, acc[1][1]);
                acc[1][2] = fmaf(pp1, vv.z, acc[1][2]); acc[1][3] = fmaf(pp1, vv.w, acc[1][3]);
                acc[2][0] = fmaf(pp2, vv.x, acc[2][0]); acc[2][1] = fmaf(pp2, vv.y, acc[2][1]);
                acc[2][2] = fmaf(pp2, vv.z, acc[2][2]); acc[2][3] = fmaf(pp2, vv.w, acc[2][3]);
                acc[3][0] = fmaf(pp3, vv.x, acc[3][0]); acc[3][1] = fmaf(pp3, vv.y, acc[3][1]);
                acc[3][2] = fmaf(pp3, vv.z, acc[3][2]); acc[3][3] = fmaf(pp3, vv.w, acc[3][3]);
            }
        }
    }

    #pragma unroll
    for (int i = 0; i < 4; i++) {
        float inv = 1.0f / l_i[i];
        float4 o;
        o.x = acc[i][0] * inv; o.y = acc[i][1] * inv;
        o.z = acc[i][2] * inv; o.w = acc[i][3] * inv;
        *(float4*)&Ob[base + (size_t)(q0 + ty * 4 + i) * Dd + tx * 4] = o;
    }
}

// ---------------- launch ----------------
extern "C" void kernel_launch(void* const* d_in, const int* in_sizes, int n_in,
                              void* d_out, int out_size, void* d_ws, size_t ws_size,
                              hipStream_t stream) {
    const float* hidden = (const float*)d_in[0];
    const float* mask   = (const float*)d_in[1];
    const float* Wq = (const float*)d_in[2];
    const float* bq = (const float*)d_in[3];
    const float* Wk = (const float*)d_in[4];
    const float* bk = (const float*)d_in[5];
    const float* Wv = (const float*)d_in[6];
    const float* bv = (const float*)d_in[7];
    const float* Wo = (const float*)d_in[8];
    const float* bo = (const float*)d_in[9];
    float* out = (float*)d_out;

    char* ws = (char*)d_ws;
    float* scal = (float*)ws;  // [0..5]=amax, [8..13]=scales
    size_t off = 1024;
    const size_t szH8 = (size_t)Mm * Dd;                  // 4 MB int8
    const size_t szW8 = (size_t)Dd * Dd;                  // 1 MB int8
    const size_t szHf = (size_t)Mm * Dd * sizeof(float);  // 16.78 MB f32
    char* hq8 = ws + off; off += szH8;
    char* Wq8 = ws + off; off += szW8;
    char* Wk8 = ws + off; off += szW8;
    char* Wv8 = ws + off; off += szW8;
    char* Wo8 = ws + off; off += szW8;
    char* aq8 = ws + off; off += szH8;
    float* qb = (float*)(ws + off); off += szHf;
    float* kb = (float*)(ws + off); off += szHf;
    float* vb = (float*)(ws + off); off += szHf;
    float* ab = (float*)(ws + off); off += szHf;

    hipMemsetAsync(scal, 0, 64, stream);

    const int nH = Mm * Dd, nW = Dd * Dd;
    amax_kernel<<<512, 256, 0, stream>>>(hidden, nH, (unsigned*)(scal + 0));
    amax_kernel<<<256, 256, 0, stream>>>(Wq, nW, (unsigned*)(scal + 1));
    amax_kernel<<<256, 256, 0, stream>>>(Wk, nW, (unsigned*)(scal + 2));
    amax_kernel<<<256, 256, 0, stream>>>(Wv, nW, (unsigned*)(scal + 3));
    amax_kernel<<<256, 256, 0, stream>>>(Wo, nW, (unsigned*)(scal + 4));
    scale_kernel<<<1, 64, 0, stream>>>(scal, 0, 8, 5);

    quant8_kernel<<<1024, 256, 0, stream>>>(hidden, hq8, scal + 8, nH / 4);
    quant8_kernel<<<512, 256, 0, stream>>>(Wq, Wq8, scal + 9,  nW / 4);
    quant8_kernel<<<512, 256, 0, stream>>>(Wk, Wk8, scal + 10, nW / 4);
    quant8_kernel<<<512, 256, 0, stream>>>(Wv, Wv8, scal + 11, nW / 4);
    quant8_kernel<<<512, 256, 0, stream>>>(Wo, Wo8, scal + 12, nW / 4);

    dim3 gg(Dd / 128, Mm / 128);
    gemm_i8<<<gg, 256, 0, stream>>>(hq8, Wq8, bq, scal + 8, scal + 9,  qb, Mm, Dd, Dd);
    gemm_i8<<<gg, 256, 0, stream>>>(hq8, Wk8, bk, scal + 8, scal + 10, kb, Mm, Dd, Dd);
    gemm_i8<<<gg, 256, 0, stream>>>(hq8, Wv8, bv, scal + 8, scal + 11, vb, Mm, Dd, Dd);

    dim3 ga(Ss / 64, Hh, Bb);
    attn_kernel<<<ga, 256, 0, stream>>>(qb, kb, vb, mask, ab);

    amax_kernel<<<512, 256, 0, stream>>>(ab, nH, (unsigned*)(scal + 5));
    scale_kernel<<<1, 64, 0, stream>>>(scal, 5, 13, 1);
    quant8_kernel<<<1024, 256, 0, stream>>>(ab, aq8, scal + 13, nH / 4);
    gemm_i8<<<gg, 256, 0, stream>>>(aq8, Wo8, bo, scal + 13, scal + 12, out, Mm, Dd, Dd);
}

// Round 3
// 408.048 us; speedup vs baseline: 3.9060x; 2.2273x over previous
//
#include <hip/hip_runtime.h>
#include <cstddef>
#include <cstdint>

// Problem constants (B=2, S=2048, D=1024, H=16, hd=64)
constexpr int Bb = 2, Ss = 2048, Dd = 1024, Hh = 16, HD = 64;
constexpr int Mm = Bb * Ss;  // 4096 rows

typedef int v4i __attribute__((ext_vector_type(4)));
typedef __bf16 bf16x8 __attribute__((ext_vector_type(8)));
typedef float f32x16 __attribute__((ext_vector_type(16)));

// ---------------- amax (abs-max) reduction, float4 ----------------
__global__ void amax_kernel(const float4* __restrict__ x, int n4, unsigned* __restrict__ out) {
    float m = 0.f;
    int stride = gridDim.x * blockDim.x;
    for (int i = blockIdx.x * blockDim.x + threadIdx.x; i < n4; i += stride) {
        float4 v = x[i];
        m = fmaxf(m, fmaxf(fmaxf(fabsf(v.x), fabsf(v.y)), fmaxf(fabsf(v.z), fabsf(v.w))));
    }
    #pragma unroll
    for (int off = 32; off > 0; off >>= 1)
        m = fmaxf(m, __shfl_down(m, off, 64));
    __shared__ float sm[8];
    int lane = threadIdx.x & 63, wid = threadIdx.x >> 6;
    if (lane == 0) sm[wid] = m;
    __syncthreads();
    if (threadIdx.x == 0) {
        float mm = sm[0];
        int nw = blockDim.x >> 6;
        for (int i = 1; i < nw; i++) mm = fmaxf(mm, sm[i]);
        atomicMax(out, __float_as_uint(mm));  // float bits compare as uint for >=0
    }
}

// scale = max(amax / 127, 1e-8)
__global__ void scale_kernel(float* ws, int amax_base, int scale_base, int cnt) {
    int i = threadIdx.x;
    if (i < cnt) ws[scale_base + i] = fmaxf(ws[amax_base + i] / 127.0f, 1e-8f);
}

// q = (int8) rint(x/s)
__global__ void quant8_kernel(const float* __restrict__ x, char* __restrict__ y,
                              const float* __restrict__ sp, int n4) {
    float s = sp[0];
    int stride = gridDim.x * blockDim.x;
    const float4* x4 = (const float4*)x;
    char4* y4 = (char4*)y;
    for (int i = blockIdx.x * blockDim.x + threadIdx.x; i < n4; i += stride) {
        float4 v = x4[i];
        char4 q;
        q.x = (char)(int)rintf(v.x / s);
        q.y = (char)(int)rintf(v.y / s);
        q.z = (char)(int)rintf(v.z / s);
        q.w = (char)(int)rintf(v.w / s);
        y4[i] = q;
    }
}

// round-to-nearest-even split of f32 into two bf16 (hi + lo)
__device__ inline void bf16split(float x, unsigned short& hi, unsigned short& lo) {
    unsigned u = __float_as_uint(x);
    unsigned h = (u + 0x7fffu + ((u >> 16) & 1u)) >> 16;
    hi = (unsigned short)h;
    float r = x - __uint_as_float(h << 16);
    unsigned v = __float_as_uint(r);
    lo = (unsigned short)((v + 0x7fffu + ((v >> 16) & 1u)) >> 16);
}

// fast truncating split+pack for p in [0,1]: u32 = (hi16 << 16) | lo16
__device__ inline unsigned packsplit(float x) {
    unsigned u = __float_as_uint(x);
    unsigned hb = u & 0xffff0000u;
    float r = x - __uint_as_float(hb);
    return hb | (__float_as_uint(r) >> 16);
}

// ---------------- int8 MFMA GEMM: C = (A_i8 . B_i8^T) * (sA*sB) + bias ----------------
// MODE 0: f32 row-major C. MODE 1: bf16 hi/lo split row-major (val *= postmul).
// MODE 2: bf16 hi/lo split, V^T layout [B,H,64,S].
#define GLOAD_LDS16(g, l) __builtin_amdgcn_global_load_lds( \
    (const __attribute__((address_space(1))) unsigned int*)(g), \
    (__attribute__((address_space(3))) unsigned int*)(l), 16, 0, 0)

template <int MODE>
__global__ __launch_bounds__(256) void gemm_i8(const char* __restrict__ A,
                                               const char* __restrict__ Bw,
                                               const float* __restrict__ bias,
                                               const float* __restrict__ sA,
                                               const float* __restrict__ sB,
                                               float postmul,
                                               float* __restrict__ Cf,
                                               unsigned short* __restrict__ Chi,
                                               unsigned short* __restrict__ Clo,
                                               int M, int N, int K) {
    __shared__ alignas(16) char At[128 * 64];
    __shared__ alignas(16) char Bt[128 * 64];
    const int t = threadIdx.x, lane = t & 63, w = t >> 6;
    const int bm = blockIdx.y * 128, bn = blockIdx.x * 128;
    const int wm = (w >> 1) * 64, wn = (w & 1) * 64;
    const int lr = lane & 15, kq = lane >> 4;

    const v4i vzero = {0, 0, 0, 0};
    v4i acc[4][4];
    #pragma unroll
    for (int mt = 0; mt < 4; mt++)
        #pragma unroll
        for (int nt = 0; nt < 4; nt++) acc[mt][nt] = vzero;

    const int rs = w * 16 + (lane >> 2);
    const int cc = lane & 3;

    for (int k0 = 0; k0 < K; k0 += 64) {
        __syncthreads();
        #pragma unroll
        for (int h = 0; h < 2; h++) {
            int r = rs + h * 64;
            int cs = cc ^ ((r >> 1) & 3);
            const char* ga = A  + (size_t)(bm + r) * K + k0 + cs * 16;
            const char* gb = Bw + (size_t)(bn + r) * K + k0 + cs * 16;
            GLOAD_LDS16(ga, At + r * 64 + cc * 16);
            GLOAD_LDS16(gb, Bt + r * 64 + cc * 16);
        }
        __syncthreads();

        v4i af[4], bf[4];
        #pragma unroll
        for (int mt = 0; mt < 4; mt++) {
            int row = wm + mt * 16 + lr;
            af[mt] = *(const v4i*)(At + row * 64 + ((kq ^ ((row >> 1) & 3)) << 4));
        }
        #pragma unroll
        for (int nt = 0; nt < 4; nt++) {
            int row = wn + nt * 16 + lr;
            bf[nt] = *(const v4i*)(Bt + row * 64 + ((kq ^ ((row >> 1) & 3)) << 4));
        }
        #pragma unroll
        for (int mt = 0; mt < 4; mt++)
            #pragma unroll
            for (int nt = 0; nt < 4; nt++)
                acc[mt][nt] = __builtin_amdgcn_mfma_i32_16x16x64_i8(af[mt], bf[nt], acc[mt][nt], 0, 0, 0);
    }

    const float sc = sA[0] * sB[0];
    #pragma unroll
    for (int nt = 0; nt < 4; nt++) {
        int n = bn + wn + nt * 16 + lr;
        float bv = bias[n];
        #pragma unroll
        for (int mt = 0; mt < 4; mt++) {
            if (MODE == 2) {
                int m0 = bm + wm + mt * 16 + kq * 4;
                int b_ = m0 >> 11, s_ = m0 & 2047;
                int e = n & 63, hc = n >> 6;
                unsigned short h4[4], l4[4];
                #pragma unroll
                for (int rg = 0; rg < 4; rg++) {
                    float val = (float)acc[mt][nt][rg] * sc + bv;
                    bf16split(val, h4[rg], l4[rg]);
                }
                size_t ad = (((size_t)(b_ * Hh + hc) * 64 + e) * Ss) + s_;
                ushort4 hv; hv.x = h4[0]; hv.y = h4[1]; hv.z = h4[2]; hv.w = h4[3];
                ushort4 lv; lv.x = l4[0]; lv.y = l4[1]; lv.z = l4[2]; lv.w = l4[3];
                *(ushort4*)(Chi + ad) = hv;
                *(ushort4*)(Clo + ad) = lv;
            } else {
                #pragma unroll
                for (int rg = 0; rg < 4; rg++) {
                    int m = bm + wm + mt * 16 + kq * 4 + rg;
                    float val = (float)acc[mt][nt][rg] * sc + bv;
                    if (MODE == 0) {
                        Cf[(size_t)m * N + n] = val;
                    } else {
                        val *= postmul;
                        unsigned short hi, lo;
                        bf16split(val, hi, lo);
                        Chi[(size_t)m * N + n] = hi;
                        Clo[(size_t)m * N + n] = lo;
                    }
                }
            }
        }
    }
}

// ---------------- MFMA flash attention, bf16 hi/lo split (3-product f32 emulation) ---------
// Block: 4 waves x 32 q-rows = 128 q-rows. mfma_f32_32x32x16_bf16.
// C/D layout: col=lane&31, row=(reg&3)+8*(reg>>2)+4*(lane>>5)  [verified m74/m101]
// A/B layout: m(n)=lane&31, k=(lane>>5)*8+j
__global__ __launch_bounds__(256) void attn_mfma(
    const unsigned short* __restrict__ qhi, const unsigned short* __restrict__ qlo,
    const unsigned short* __restrict__ khi, const unsigned short* __restrict__ klo,
    const unsigned short* __restrict__ vthi, const unsigned short* __restrict__ vtlo,
    const float* __restrict__ mask, float* __restrict__ Ob, unsigned* __restrict__ amax_out) {
    __shared__ alignas(16) unsigned short KsHi[64][72], KsLo[64][72];
    __shared__ alignas(16) unsigned short VsHi[64][72], VsLo[64][72];
    __shared__ alignas(16) unsigned Pw[4][32][68];
    __shared__ float mbias[64];
    __shared__ float wred[4];

    const int t = threadIdx.x, lane = t & 63, wq = t >> 6;
    const int ln31 = lane & 31, h5 = lane >> 5;
    const int b = blockIdx.z, h = blockIdx.y, q0 = blockIdx.x * 128;

    // preload Q fragments (A operand): row = q0 + wq*32 + ln31, k = c*16 + h5*8 + j
    bf16x8 qfh[4], qfl[4];
    {
        int qrow = q0 + wq * 32 + ln31;
        const unsigned short* qb_ = qhi + ((size_t)(b * Ss + qrow)) * Dd + h * 64 + h5 * 8;
        const unsigned short* ql_ = qlo + ((size_t)(b * Ss + qrow)) * Dd + h * 64 + h5 * 8;
        #pragma unroll
        for (int c = 0; c < 4; c++) {
            qfh[c] = *(const bf16x8*)(qb_ + c * 16);
            qfl[c] = *(const bf16x8*)(ql_ + c * 16);
        }
    }

    f32x16 o0 = 0.f, o1 = 0.f;
    float m_i[16], l_i[16];
    #pragma unroll
    for (int r = 0; r < 16; r++) { m_i[r] = -INFINITY; l_i[r] = 0.f; }

    for (int k0 = 0; k0 < Ss; k0 += 64) {
        __syncthreads();
        {   // stage K and V^T tiles (hi+lo) into LDS
            int r = t >> 2, cp = (t & 3) * 2;  // rows 0..63, chunk pairs
            const unsigned short* gk = khi + ((size_t)(b * Ss + k0 + r)) * Dd + h * 64 + cp * 8;
            const unsigned short* gkl = klo + ((size_t)(b * Ss + k0 + r)) * Dd + h * 64 + cp * 8;
            const unsigned short* gv = vthi + (((size_t)(b * Hh + h) * 64 + r)) * Ss + k0 + cp * 8;
            const unsigned short* gvl = vtlo + (((size_t)(b * Hh + h) * 64 + r)) * Ss + k0 + cp * 8;
            *(int4*)&KsHi[r][cp * 8] = *(const int4*)gk;
            *(int4*)&KsHi[r][cp * 8 + 8] = *(const int4*)(gk + 8);
            *(int4*)&KsLo[r][cp * 8] = *(const int4*)gkl;
            *(int4*)&KsLo[r][cp * 8 + 8] = *(const int4*)(gkl + 8);
            *(int4*)&VsHi[r][cp * 8] = *(const int4*)gv;
            *(int4*)&VsHi[r][cp * 8 + 8] = *(const int4*)(gv + 8);
            *(int4*)&VsLo[r][cp * 8] = *(const int4*)gvl;
            *(int4*)&VsLo[r][cp * 8 + 8] = *(const int4*)(gvl + 8);
            if (t < 64) mbias[t] = (1.0f - mask[b * Ss + k0 + t]) * -10000.0f;
        }
        __syncthreads();

        // QK^T: two 32x32 score tiles (cols ct*32)
        f32x16 sc0 = 0.f, sc1 = 0.f;
        #pragma unroll
        for (int c = 0; c < 4; c++) {
            bf16x8 kh0 = *(const bf16x8*)&KsHi[ln31][c * 16 + h5 * 8];
            bf16x8 kl0 = *(const bf16x8*)&KsLo[ln31][c * 16 + h5 * 8];
            bf16x8 kh1 = *(const bf16x8*)&KsHi[32 + ln31][c * 16 + h5 * 8];
            bf16x8 kl1 = *(const bf16x8*)&KsLo[32 + ln31][c * 16 + h5 * 8];
            sc0 = __builtin_amdgcn_mfma_f32_32x32x16_bf16(qfl[c], kh0, sc0, 0, 0, 0);
            sc0 = __builtin_amdgcn_mfma_f32_32x32x16_bf16(qfh[c], kl0, sc0, 0, 0, 0);
            sc0 = __builtin_amdgcn_mfma_f32_32x32x16_bf16(qfh[c], kh0, sc0, 0, 0, 0);
            sc1 = __builtin_amdgcn_mfma_f32_32x32x16_bf16(qfl[c], kh1, sc1, 0, 0, 0);
            sc1 = __builtin_amdgcn_mfma_f32_32x32x16_bf16(qfh[c], kl1, sc1, 0, 0, 0);
            sc1 = __builtin_amdgcn_mfma_f32_32x32x16_bf16(qfh[c], kh1, sc1, 0, 0, 0);
        }

        // online softmax, P pack+write to per-wave LDS
        float mb0 = mbias[ln31], mb1 = mbias[32 + ln31];
        #pragma unroll
        for (int r = 0; r < 16; r++) {
            float s0 = sc0[r] + mb0, s1 = sc1[r] + mb1;
            float tm = fmaxf(s0, s1);
            #pragma unroll
            for (int off = 1; off < 32; off <<= 1) tm = fmaxf(tm, __shfl_xor(tm, off, 32));
            float mnew = fmaxf(m_i[r], tm);
            float al = __expf(m_i[r] - mnew);
            float p0 = __expf(s0 - mnew), p1 = __expf(s1 - mnew);
            float rs = p0 + p1;
            #pragma unroll
            for (int off = 1; off < 32; off <<= 1) rs += __shfl_xor(rs, off, 32);
            l_i[r] = l_i[r] * al + rs;
            m_i[r] = mnew;
            o0[r] *= al;
            o1[r] *= al;
            int row = (r & 3) + 8 * (r >> 2) + 4 * h5;
            Pw[wq][row][ln31] = packsplit(p0);
            Pw[wq][row][32 + ln31] = packsplit(p1);
        }

        // PV: O += P * V  (P A-frags from per-wave LDS; compiler inserts lgkmcnt)
        #pragma unroll
        for (int c = 0; c < 4; c++) {
            const int4* pp = (const int4*)&Pw[wq][ln31][c * 16 + h5 * 8];
            int4 w0 = pp[0], w1 = pp[1];
            unsigned wv[8] = {(unsigned)w0.x, (unsigned)w0.y, (unsigned)w0.z, (unsigned)w0.w,
                              (unsigned)w1.x, (unsigned)w1.y, (unsigned)w1.z, (unsigned)w1.w};
            union { unsigned short u[8]; bf16x8 v; } ph, pl;
            #pragma unroll
            for (int j = 0; j < 8; j++) {
                ph.u[j] = (unsigned short)(wv[j] >> 16);
                pl.u[j] = (unsigned short)(wv[j] & 0xffffu);
            }
            #pragma unroll
            for (int et = 0; et < 2; et++) {
                bf16x8 vh = *(const bf16x8*)&VsHi[et * 32 + ln31][c * 16 + h5 * 8];
                bf16x8 vl = *(const bf16x8*)&VsLo[et * 32 + ln31][c * 16 + h5 * 8];
                if (et == 0) {
                    o0 = __builtin_amdgcn_mfma_f32_32x32x16_bf16(pl.v, vh, o0, 0, 0, 0);
                    o0 = __builtin_amdgcn_mfma_f32_32x32x16_bf16(ph.v, vl, o0, 0, 0, 0);
                    o0 = __builtin_amdgcn_mfma_f32_32x32x16_bf16(ph.v, vh, o0, 0, 0, 0);
                } else {
                    o1 = __builtin_amdgcn_mfma_f32_32x32x16_bf16(pl.v, vh, o1, 0, 0, 0);
                    o1 = __builtin_amdgcn_mfma_f32_32x32x16_bf16(ph.v, vl, o1, 0, 0, 0);
                    o1 = __builtin_amdgcn_mfma_f32_32x32x16_bf16(ph.v, vh, o1, 0, 0, 0);
                }
            }
        }
    }

    // epilogue: normalize, write, fused block amax
    float lmax = 0.f;
    #pragma unroll
    for (int r = 0; r < 16; r++) {
        float inv = 1.0f / l_i[r];
        int row = q0 + wq * 32 + (r & 3) + 8 * (r >> 2) + 4 * h5;
        size_t ro = ((size_t)(b * Ss + row)) * Dd + h * 64;
        float v0 = o0[r] * inv, v1 = o1[r] * inv;
        Ob[ro + ln31] = v0;
        Ob[ro + 32 + ln31] = v1;
        lmax = fmaxf(lmax, fmaxf(fabsf(v0), fabsf(v1)));
    }
    #pragma unroll
    for (int off = 32; off > 0; off >>= 1) lmax = fmaxf(lmax, __shfl_xor(lmax, off, 64));
    if (lane == 0) wred[wq] = lmax;
    __syncthreads();
    if (t == 0) {
        float m = fmaxf(fmaxf(wred[0], wred[1]), fmaxf(wred[2], wred[3]));
        atomicMax(amax_out, __float_as_uint(m));
    }
}

// ---------------- launch ----------------
extern "C" void kernel_launch(void* const* d_in, const int* in_sizes, int n_in,
                              void* d_out, int out_size, void* d_ws, size_t ws_size,
                              hipStream_t stream) {
    const float* hidden = (const float*)d_in[0];
    const float* mask   = (const float*)d_in[1];
    const float* Wq = (const float*)d_in[2];
    const float* bq = (const float*)d_in[3];
    const float* Wk = (const float*)d_in[4];
    const float* bk = (const float*)d_in[5];
    const float* Wv = (const float*)d_in[6];
    const float* bv = (const float*)d_in[7];
    const float* Wo = (const float*)d_in[8];
    const float* bo = (const float*)d_in[9];
    float* out = (float*)d_out;

    char* ws = (char*)d_ws;
    float* scal = (float*)ws;  // [0..5]=amax, [8..13]=scales
    size_t off = 1024;
    const size_t szH8 = (size_t)Mm * Dd;                       // 4 MB
    const size_t szW8 = (size_t)Dd * Dd;                       // 1 MB
    const size_t szHb = (size_t)Mm * Dd * sizeof(unsigned short);  // 8.39 MB
    const size_t szHf = (size_t)Mm * Dd * sizeof(float);       // 16.78 MB
    char* hq8 = ws + off; off += szH8;
    char* Wq8 = ws + off; off += szW8;
    char* Wk8 = ws + off; off += szW8;
    char* Wv8 = ws + off; off += szW8;
    char* Wo8 = ws + off; off += szW8;
    char* aq8 = ws + off; off += szH8;
    unsigned short* qhi = (unsigned short*)(ws + off); off += szHb;
    unsigned short* qlo = (unsigned short*)(ws + off); off += szHb;
    unsigned short* khi = (unsigned short*)(ws + off); off += szHb;
    unsigned short* klo = (unsigned short*)(ws + off); off += szHb;
    unsigned short* vthi = (unsigned short*)(ws + off); off += szHb;
    unsigned short* vtlo = (unsigned short*)(ws + off); off += szHb;
    float* ab = (float*)(ws + off); off += szHf;

    hipMemsetAsync(scal, 0, 64, stream);

    const int nH = Mm * Dd, nW = Dd * Dd;
    amax_kernel<<<256, 256, 0, stream>>>((const float4*)hidden, nH / 4, (unsigned*)(scal + 0));
    amax_kernel<<<128, 256, 0, stream>>>((const float4*)Wq, nW / 4, (unsigned*)(scal + 1));
    amax_kernel<<<128, 256, 0, stream>>>((const float4*)Wk, nW / 4, (unsigned*)(scal + 2));
    amax_kernel<<<128, 256, 0, stream>>>((const float4*)Wv, nW / 4, (unsigned*)(scal + 3));
    amax_kernel<<<128, 256, 0, stream>>>((const float4*)Wo, nW / 4, (unsigned*)(scal + 4));
    scale_kernel<<<1, 64, 0, stream>>>(scal, 0, 8, 5);

    quant8_kernel<<<1024, 256, 0, stream>>>(hidden, hq8, scal + 8, nH / 4);
    quant8_kernel<<<512, 256, 0, stream>>>(Wq, Wq8, scal + 9,  nW / 4);
    quant8_kernel<<<512, 256, 0, stream>>>(Wk, Wk8, scal + 10, nW / 4);
    quant8_kernel<<<512, 256, 0, stream>>>(Wv, Wv8, scal + 11, nW / 4);
    quant8_kernel<<<512, 256, 0, stream>>>(Wo, Wo8, scal + 12, nW / 4);

    dim3 gg(Dd / 128, Mm / 128);
    gemm_i8<1><<<gg, 256, 0, stream>>>(hq8, Wq8, bq, scal + 8, scal + 9,  0.125f, nullptr, qhi, qlo, Mm, Dd, Dd);
    gemm_i8<1><<<gg, 256, 0, stream>>>(hq8, Wk8, bk, scal + 8, scal + 10, 1.0f,   nullptr, khi, klo, Mm, Dd, Dd);
    gemm_i8<2><<<gg, 256, 0, stream>>>(hq8, Wv8, bv, scal + 8, scal + 11, 1.0f,   nullptr, vthi, vtlo, Mm, Dd, Dd);

    dim3 ga(Ss / 128, Hh, Bb);
    attn_mfma<<<ga, 256, 0, stream>>>(qhi, qlo, khi, klo, vthi, vtlo, mask, ab, (unsigned*)(scal + 5));

    scale_kernel<<<1, 64, 0, stream>>>(scal, 5, 13, 1);
    quant8_kernel<<<1024, 256, 0, stream>>>(ab, aq8, scal + 13, nH / 4);
    gemm_i8<0><<<gg, 256, 0, stream>>>(aq8, Wo8, bo, scal + 13, scal + 12, 1.0f, out, nullptr, nullptr, Mm, Dd, Dd);
}

// Round 4
// 253.686 us; speedup vs baseline: 6.2827x; 1.6085x over previous
//
#include <hip/hip_runtime.h>
#include <cstddef>
#include <cstdint>

// Problem constants (B=2, S=2048, D=1024, H=16, hd=64)
constexpr int Bb = 2, Ss = 2048, Dd = 1024, Hh = 16, HD = 64;
constexpr int Mm = Bb * Ss;  // 4096 rows

typedef int v4i __attribute__((ext_vector_type(4)));
typedef __bf16 bf16x8 __attribute__((ext_vector_type(8)));
typedef float f32x16 __attribute__((ext_vector_type(16)));

// ln2 folding: q *= 0.125 * 1/ln2 so p = exp2(score) is one v_exp_f32
#define QPOSTMUL 0.18033688f
#define MASKBIAS -14426.950408f   /* -10000 / ln2 */

__device__ __forceinline__ float qscale(float amax) {
    return fmaxf(amax / 127.0f, 1e-8f);
}

// round-to-nearest-even f32 -> bf16 bits
__device__ __forceinline__ unsigned short bf16rtn(float x) {
    __bf16 b = (__bf16)x;
    return __builtin_bit_cast(unsigned short, b);
}

// RTN split of f32 into two bf16 (hi + lo), hi+lo == x to ~2^-16 rel
__device__ __forceinline__ void bf16split(float x, unsigned short& hi, unsigned short& lo) {
    unsigned u = __float_as_uint(x);
    unsigned h = (u + 0x7fffu + ((u >> 16) & 1u)) >> 16;
    hi = (unsigned short)h;
    float r = x - __uint_as_float(h << 16);
    unsigned v = __float_as_uint(r);
    lo = (unsigned short)((v + 0x7fffu + ((v >> 16) & 1u)) >> 16);
}

// ---------------- fused amax: hidden (slot0) + 4 weights (slots 1-4) ----------------
__global__ void amax_all(const float4* __restrict__ hidden,
                         const float4* __restrict__ w0, const float4* __restrict__ w1,
                         const float4* __restrict__ w2, const float4* __restrict__ w3,
                         unsigned* __restrict__ slots) {
    const float4* src; int n4, slot, bx, nb;
    if (blockIdx.x < 256) { src = hidden; n4 = Mm * Dd / 4; slot = 0; bx = blockIdx.x; nb = 256; }
    else {
        int w = (blockIdx.x - 256) >> 4; bx = (blockIdx.x - 256) & 15; nb = 16;
        src = w == 0 ? w0 : w == 1 ? w1 : w == 2 ? w2 : w3;
        n4 = Dd * Dd / 4; slot = 1 + w;
    }
    float m = 0.f;
    for (int i = bx * blockDim.x + threadIdx.x; i < n4; i += nb * blockDim.x) {
        float4 v = src[i];
        m = fmaxf(m, fmaxf(fmaxf(fabsf(v.x), fabsf(v.y)), fmaxf(fabsf(v.z), fabsf(v.w))));
    }
    #pragma unroll
    for (int off = 32; off > 0; off >>= 1) m = fmaxf(m, __shfl_down(m, off, 64));
    __shared__ float sm[4];
    int lane = threadIdx.x & 63, wid = threadIdx.x >> 6;
    if (lane == 0) sm[wid] = m;
    __syncthreads();
    if (threadIdx.x == 0) {
        float mm = fmaxf(fmaxf(sm[0], sm[1]), fmaxf(sm[2], sm[3]));
        atomicMax(slots + slot, __float_as_uint(mm));  // f32 bits compare as uint for >=0
    }
}

// ---------------- fused quant: hidden -> hq8, 4 weights -> Wall8 (1MB apart) ------------
__global__ void quant_all(const float* __restrict__ hidden,
                          const float* __restrict__ w0, const float* __restrict__ w1,
                          const float* __restrict__ w2, const float* __restrict__ w3,
                          const float* __restrict__ amax,
                          char* __restrict__ hq8, char* __restrict__ Wall8) {
    const float* x; char* y; int n4, slot, bx, nb;
    if (blockIdx.x < 1024) { x = hidden; y = hq8; n4 = Mm * Dd / 4; slot = 0; bx = blockIdx.x; nb = 1024; }
    else {
        int w = (blockIdx.x - 1024) >> 5; bx = (blockIdx.x - 1024) & 31; nb = 32;
        x = w == 0 ? w0 : w == 1 ? w1 : w == 2 ? w2 : w3;
        y = Wall8 + ((size_t)w << 20);
        n4 = Dd * Dd / 4; slot = 1 + w;
    }
    float s = qscale(amax[slot]);
    const float4* x4 = (const float4*)x;
    char4* y4 = (char4*)y;
    for (int i = bx * blockDim.x + threadIdx.x; i < n4; i += nb * blockDim.x) {
        float4 v = x4[i];
        char4 q;
        q.x = (char)(int)rintf(v.x / s);
        q.y = (char)(int)rintf(v.y / s);
        q.z = (char)(int)rintf(v.z / s);
        q.w = (char)(int)rintf(v.w / s);
        y4[i] = q;
    }
}

// quant attn output (scale inline from amax slot)
__global__ void quant_a(const float* __restrict__ x, char* __restrict__ y,
                        const float* __restrict__ amax, int n4) {
    float s = qscale(amax[0]);
    int stride = gridDim.x * blockDim.x;
    const float4* x4 = (const float4*)x;
    char4* y4 = (char4*)y;
    for (int i = blockIdx.x * blockDim.x + threadIdx.x; i < n4; i += stride) {
        float4 v = x4[i];
        char4 q;
        q.x = (char)(int)rintf(v.x / s);
        q.y = (char)(int)rintf(v.y / s);
        q.z = (char)(int)rintf(v.z / s);
        q.w = (char)(int)rintf(v.w / s);
        y4[i] = q;
    }
}

// ---------------- shared int8 MFMA GEMM core (128x128 tile, BK=64, 4 waves) -------------
#define GLOAD_LDS16(g, l) __builtin_amdgcn_global_load_lds( \
    (const __attribute__((address_space(1))) unsigned int*)(g), \
    (__attribute__((address_space(3))) unsigned int*)(l), 16, 0, 0)

__device__ __forceinline__ void gemm_i8_core(const char* __restrict__ A, const char* __restrict__ Bw,
                                             int bm, int bn, int K, int t,
                                             char* At, char* Bt, v4i acc[4][4]) {
    const int lane = t & 63, w = t >> 6;
    const int wm = (w >> 1) * 64, wn = (w & 1) * 64;
    const int lr = lane & 15, kq = lane >> 4;
    const int rs = w * 16 + (lane >> 2);
    const int cc = lane & 3;

    for (int k0 = 0; k0 < K; k0 += 64) {
        __syncthreads();
        #pragma unroll
        for (int h = 0; h < 2; h++) {
            int r = rs + h * 64;
            int cs = cc ^ ((r >> 1) & 3);  // source-side XOR swizzle
            const char* ga = A  + (size_t)(bm + r) * K + k0 + cs * 16;
            const char* gb = Bw + (size_t)(bn + r) * K + k0 + cs * 16;
            GLOAD_LDS16(ga, At + r * 64 + cc * 16);
            GLOAD_LDS16(gb, Bt + r * 64 + cc * 16);
        }
        __syncthreads();

        v4i af[4], bf[4];
        #pragma unroll
        for (int mt = 0; mt < 4; mt++) {
            int row = wm + mt * 16 + lr;
            af[mt] = *(const v4i*)(At + row * 64 + ((kq ^ ((row >> 1) & 3)) << 4));
        }
        #pragma unroll
        for (int nt = 0; nt < 4; nt++) {
            int row = wn + nt * 16 + lr;
            bf[nt] = *(const v4i*)(Bt + row * 64 + ((kq ^ ((row >> 1) & 3)) << 4));
        }
        #pragma unroll
        for (int mt = 0; mt < 4; mt++)
            #pragma unroll
            for (int nt = 0; nt < 4; nt++)
                acc[mt][nt] = __builtin_amdgcn_mfma_i32_16x16x64_i8(af[mt], bf[nt], acc[mt][nt], 0, 0, 0);
    }
}

// Fused Q/K/V projection: blockIdx.x -> {mat, col-block}. Q,K: bf16 hi/lo split rows;
// V: bf16 (hi-only) transposed [B,H,64,S].
__global__ __launch_bounds__(256) void gemm_qkv(const char* __restrict__ A,
                                                const char* __restrict__ Wall8,
                                                const float* __restrict__ bq,
                                                const float* __restrict__ bk,
                                                const float* __restrict__ bv,
                                                const float* __restrict__ amax,
                                                unsigned short* __restrict__ qhi,
                                                unsigned short* __restrict__ qlo,
                                                unsigned short* __restrict__ khi,
                                                unsigned short* __restrict__ klo,
                                                unsigned short* __restrict__ vthi) {
    __shared__ alignas(16) char At[128 * 64];
    __shared__ alignas(16) char Bt[128 * 64];
    const int t = threadIdx.x, lane = t & 63, w = t >> 6;
    const int mat = blockIdx.x >> 3;
    const int bn = (blockIdx.x & 7) * 128, bm = blockIdx.y * 128;
    const int wm = (w >> 1) * 64, wn = (w & 1) * 64;
    const int lr = lane & 15, kq = lane >> 4;

    const v4i vzero = {0, 0, 0, 0};
    v4i acc[4][4];
    #pragma unroll
    for (int mt = 0; mt < 4; mt++)
        #pragma unroll
        for (int nt = 0; nt < 4; nt++) acc[mt][nt] = vzero;

    const char* Bw = Wall8 + ((size_t)mat << 20);
    gemm_i8_core(A, Bw, bm, bn, Dd, t, At, Bt, acc);

    const float* bias = mat == 0 ? bq : mat == 1 ? bk : bv;
    float sc = qscale(amax[0]) * qscale(amax[1 + mat]);
    float pm = (mat == 0) ? QPOSTMUL : 1.0f;  // fold 0.125/ln2 into Q

    #pragma unroll
    for (int nt = 0; nt < 4; nt++) {
        int n = bn + wn + nt * 16 + lr;
        float bv_ = bias[n];
        #pragma unroll
        for (int mt = 0; mt < 4; mt++) {
            if (mat == 2) {  // V^T, bf16 hi only
                int m0 = bm + wm + mt * 16 + kq * 4;
                int b_ = m0 >> 11, s_ = m0 & 2047;
                int e = n & 63, hc = n >> 6;
                ushort4 hv;
                hv.x = bf16rtn((float)acc[mt][nt][0] * sc + bv_);
                hv.y = bf16rtn((float)acc[mt][nt][1] * sc + bv_);
                hv.z = bf16rtn((float)acc[mt][nt][2] * sc + bv_);
                hv.w = bf16rtn((float)acc[mt][nt][3] * sc + bv_);
                size_t ad = (((size_t)(b_ * Hh + hc) * 64 + e) * Ss) + s_;
                *(ushort4*)(vthi + ad) = hv;
            } else {
                unsigned short* Chi = mat == 0 ? qhi : khi;
                unsigned short* Clo = mat == 0 ? qlo : klo;
                #pragma unroll
                for (int rg = 0; rg < 4; rg++) {
                    int m = bm + wm + mt * 16 + kq * 4 + rg;
                    float val = ((float)acc[mt][nt][rg] * sc + bv_) * pm;
                    unsigned short hi, lo;
                    bf16split(val, hi, lo);
                    Chi[(size_t)m * Dd + n] = hi;
                    Clo[(size_t)m * Dd + n] = lo;
                }
            }
        }
    }
}

// O-projection: f32 output
__global__ __launch_bounds__(256) void gemm_o(const char* __restrict__ A,
                                              const char* __restrict__ Bw,
                                              const float* __restrict__ bias,
                                              const float* __restrict__ amaxA,
                                              const float* __restrict__ amaxB,
                                              float* __restrict__ C) {
    __shared__ alignas(16) char At[128 * 64];
    __shared__ alignas(16) char Bt[128 * 64];
    const int t = threadIdx.x, lane = t & 63, w = t >> 6;
    const int bn = blockIdx.x * 128, bm = blockIdx.y * 128;
    const int wm = (w >> 1) * 64, wn = (w & 1) * 64;
    const int lr = lane & 15, kq = lane >> 4;

    const v4i vzero = {0, 0, 0, 0};
    v4i acc[4][4];
    #pragma unroll
    for (int mt = 0; mt < 4; mt++)
        #pragma unroll
        for (int nt = 0; nt < 4; nt++) acc[mt][nt] = vzero;

    gemm_i8_core(A, Bw, bm, bn, Dd, t, At, Bt, acc);

    float sc = qscale(amaxA[0]) * qscale(amaxB[0]);
    #pragma unroll
    for (int nt = 0; nt < 4; nt++) {
        int n = bn + wn + nt * 16 + lr;
        float bv_ = bias[n];
        #pragma unroll
        for (int mt = 0; mt < 4; mt++)
            #pragma unroll
            for (int rg = 0; rg < 4; rg++) {
                int m = bm + wm + mt * 16 + kq * 4 + rg;
                C[(size_t)m * Dd + n] = (float)acc[mt][nt][rg] * sc + bv_;
            }
    }
}

// ---------------- MFMA flash attention, no-max softmax (exp2 logits) --------------------
// QK^T: bf16 hi/lo 3-product (f32-accurate logits). PV: single bf16 (unbiased ~3e-5 err).
// No running max / rescale: l accumulated per-lane, reduced once at the end.
__global__ __launch_bounds__(256) void attn_mfma(
    const unsigned short* __restrict__ qhi, const unsigned short* __restrict__ qlo,
    const unsigned short* __restrict__ khi, const unsigned short* __restrict__ klo,
    const unsigned short* __restrict__ vthi,
    const float* __restrict__ mask, float* __restrict__ Ob, unsigned* __restrict__ amax_out) {
    __shared__ alignas(16) unsigned short KsHi[64][72], KsLo[64][72], VsHi[64][72];
    __shared__ alignas(16) unsigned short Pw[4][32][72];
    __shared__ float mbias[64];
    __shared__ float wred[4];

    const int t = threadIdx.x, lane = t & 63, wq = t >> 6;
    const int ln31 = lane & 31, h5 = lane >> 5;
    const int b = blockIdx.z, h = blockIdx.y, q0 = blockIdx.x * 128;

    // Q fragments (A operand): row = q0 + wq*32 + ln31, k = c*16 + h5*8 + j
    bf16x8 qfh[4], qfl[4];
    {
        int qrow = q0 + wq * 32 + ln31;
        const unsigned short* qb_ = qhi + ((size_t)(b * Ss + qrow)) * Dd + h * 64 + h5 * 8;
        const unsigned short* ql_ = qlo + ((size_t)(b * Ss + qrow)) * Dd + h * 64 + h5 * 8;
        #pragma unroll
        for (int c = 0; c < 4; c++) {
            qfh[c] = *(const bf16x8*)(qb_ + c * 16);
            qfl[c] = *(const bf16x8*)(ql_ + c * 16);
        }
    }

    f32x16 o0 = 0.f, o1 = 0.f;
    float lp[16];
    #pragma unroll
    for (int r = 0; r < 16; r++) lp[r] = 0.f;

    for (int k0 = 0; k0 < Ss; k0 += 64) {
        __syncthreads();
        {   // stage K (hi+lo) and V^T (hi) tiles
            int r = t >> 2, cp = (t & 3) * 2;
            const unsigned short* gk  = khi + ((size_t)(b * Ss + k0 + r)) * Dd + h * 64 + cp * 8;
            const unsigned short* gkl = klo + ((size_t)(b * Ss + k0 + r)) * Dd + h * 64 + cp * 8;
            const unsigned short* gv  = vthi + (((size_t)(b * Hh + h) * 64 + r)) * Ss + k0 + cp * 8;
            *(int4*)&KsHi[r][cp * 8]     = *(const int4*)gk;
            *(int4*)&KsHi[r][cp * 8 + 8] = *(const int4*)(gk + 8);
            *(int4*)&KsLo[r][cp * 8]     = *(const int4*)gkl;
            *(int4*)&KsLo[r][cp * 8 + 8] = *(const int4*)(gkl + 8);
            *(int4*)&VsHi[r][cp * 8]     = *(const int4*)gv;
            *(int4*)&VsHi[r][cp * 8 + 8] = *(const int4*)(gv + 8);
            if (t < 64) mbias[t] = (1.0f - mask[b * Ss + k0 + t]) * MASKBIAS;
        }
        __syncthreads();

        // QK^T: two 32x32 logit tiles (pre-scaled by 1/ln2 via Q)
        f32x16 sc0 = 0.f, sc1 = 0.f;
        #pragma unroll
        for (int c = 0; c < 4; c++) {
            bf16x8 kh0 = *(const bf16x8*)&KsHi[ln31][c * 16 + h5 * 8];
            bf16x8 kl0 = *(const bf16x8*)&KsLo[ln31][c * 16 + h5 * 8];
            bf16x8 kh1 = *(const bf16x8*)&KsHi[32 + ln31][c * 16 + h5 * 8];
            bf16x8 kl1 = *(const bf16x8*)&KsLo[32 + ln31][c * 16 + h5 * 8];
            sc0 = __builtin_amdgcn_mfma_f32_32x32x16_bf16(qfl[c], kh0, sc0, 0, 0, 0);
            sc0 = __builtin_amdgcn_mfma_f32_32x32x16_bf16(qfh[c], kl0, sc0, 0, 0, 0);
            sc0 = __builtin_amdgcn_mfma_f32_32x32x16_bf16(qfh[c], kh0, sc0, 0, 0, 0);
            sc1 = __builtin_amdgcn_mfma_f32_32x32x16_bf16(qfl[c], kh1, sc1, 0, 0, 0);
            sc1 = __builtin_amdgcn_mfma_f32_32x32x16_bf16(qfh[c], kl1, sc1, 0, 0, 0);
            sc1 = __builtin_amdgcn_mfma_f32_32x32x16_bf16(qfh[c], kh1, sc1, 0, 0, 0);
        }

        // softmax numerator: p = exp2(logit + mbias), accumulate l per-lane, store bf16 P
        float mb0 = mbias[ln31], mb1 = mbias[32 + ln31];
        #pragma unroll
        for (int r = 0; r < 16; r++) {
            float p0 = __builtin_amdgcn_exp2f(sc0[r] + mb0);
            float p1 = __builtin_amdgcn_exp2f(sc1[r] + mb1);
            lp[r] += p0 + p1;
            int row = (r & 3) + 8 * (r >> 2) + 4 * h5;
            Pw[wq][row][ln31] = bf16rtn(p0);
            Pw[wq][row][32 + ln31] = bf16rtn(p1);
        }

        // PV: O += P * V (per-wave Pw, wave-internal DS ordering; no barrier needed)
        #pragma unroll
        for (int c = 0; c < 4; c++) {
            bf16x8 pf = *(const bf16x8*)&Pw[wq][ln31][c * 16 + h5 * 8];
            bf16x8 vh0 = *(const bf16x8*)&VsHi[ln31][c * 16 + h5 * 8];
            bf16x8 vh1 = *(const bf16x8*)&VsHi[32 + ln31][c * 16 + h5 * 8];
            o0 = __builtin_amdgcn_mfma_f32_32x32x16_bf16(pf, vh0, o0, 0, 0, 0);
            o1 = __builtin_amdgcn_mfma_f32_32x32x16_bf16(pf, vh1, o1, 0, 0, 0);
        }
    }

    // epilogue: reduce l across the 32 lanes holding each row, normalize, write, fused amax
    float lmax = 0.f;
    #pragma unroll
    for (int r = 0; r < 16; r++) {
        float l = lp[r];
        #pragma unroll
        for (int off = 1; off < 32; off <<= 1) l += __shfl_xor(l, off, 32);
        float inv = 1.0f / l;
        int row = q0 + wq * 32 + (r & 3) + 8 * (r >> 2) + 4 * h5;
        size_t ro = ((size_t)(b * Ss + row)) * Dd + h * 64;
        float v0 = o0[r] * inv, v1 = o1[r] * inv;
        Ob[ro + ln31] = v0;
        Ob[ro + 32 + ln31] = v1;
        lmax = fmaxf(lmax, fmaxf(fabsf(v0), fabsf(v1)));
    }
    #pragma unroll
    for (int off = 32; off > 0; off >>= 1) lmax = fmaxf(lmax, __shfl_xor(lmax, off, 64));
    if (lane == 0) wred[wq] = lmax;
    __syncthreads();
    if (t == 0) {
        float m = fmaxf(fmaxf(wred[0], wred[1]), fmaxf(wred[2], wred[3]));
        atomicMax(amax_out, __float_as_uint(m));
    }
}

// ---------------- launch ----------------
extern "C" void kernel_launch(void* const* d_in, const int* in_sizes, int n_in,
                              void* d_out, int out_size, void* d_ws, size_t ws_size,
                              hipStream_t stream) {
    const float* hidden = (const float*)d_in[0];
    const float* mask   = (const float*)d_in[1];
    const float* Wq = (const float*)d_in[2];
    const float* bq = (const float*)d_in[3];
    const float* Wk = (const float*)d_in[4];
    const float* bk = (const float*)d_in[5];
    const float* Wv = (const float*)d_in[6];
    const float* bv = (const float*)d_in[7];
    const float* Wo = (const float*)d_in[8];
    const float* bo = (const float*)d_in[9];
    float* out = (float*)d_out;

    char* ws = (char*)d_ws;
    float* scal = (float*)ws;  // amax slots 0..5
    size_t off = 1024;
    const size_t szH8 = (size_t)Mm * Dd;                           // 4 MB
    const size_t szHb = (size_t)Mm * Dd * sizeof(unsigned short);  // 8.39 MB
    const size_t szHf = (size_t)Mm * Dd * sizeof(float);           // 16.78 MB
    char* hq8   = ws + off; off += szH8;
    char* Wall8 = ws + off; off += 4u << 20;  // Wq|Wk|Wv|Wo, 1MB each
    char* aq8   = ws + off; off += szH8;
    unsigned short* qhi  = (unsigned short*)(ws + off); off += szHb;
    unsigned short* qlo  = (unsigned short*)(ws + off); off += szHb;
    unsigned short* khi  = (unsigned short*)(ws + off); off += szHb;
    unsigned short* klo  = (unsigned short*)(ws + off); off += szHb;
    unsigned short* vthi = (unsigned short*)(ws + off); off += szHb;
    float* ab = (float*)(ws + off); off += szHf;

    hipMemsetAsync(scal, 0, 64, stream);

    amax_all<<<320, 256, 0, stream>>>((const float4*)hidden, (const float4*)Wq,
                                      (const float4*)Wk, (const float4*)Wv, (const float4*)Wo,
                                      (unsigned*)scal);
    quant_all<<<1152, 256, 0, stream>>>(hidden, Wq, Wk, Wv, Wo, scal, hq8, Wall8);

    gemm_qkv<<<dim3(24, 32), 256, 0, stream>>>(hq8, Wall8, bq, bk, bv, scal,
                                               qhi, qlo, khi, klo, vthi);

    attn_mfma<<<dim3(Ss / 128, Hh, Bb), 256, 0, stream>>>(qhi, qlo, khi, klo, vthi,
                                                          mask, ab, (unsigned*)(scal + 5));

    quant_a<<<1024, 256, 0, stream>>>(ab, aq8, scal + 5, Mm * Dd / 4);

    gemm_o<<<dim3(8, 32), 256, 0, stream>>>(aq8, Wall8 + (3u << 20), bo,
                                            scal + 5, scal + 4, out);
}